// Round 14
// baseline (238.145 us; speedup 1.0000x reference)
//
#include <hip/hip_runtime.h>
#include <hip/hip_bf16.h>
#include <stdint.h>

typedef __bf16 bf16_t;
typedef __bf16 bf16x4 __attribute__((ext_vector_type(4)));
typedef __bf16 bf16x8 __attribute__((ext_vector_type(8)));
typedef float f32x4 __attribute__((ext_vector_type(4)));

#define MFMA_16x16x32(A, B, C) __builtin_amdgcn_mfma_f32_16x16x32_bf16(A, B, C, 0, 0, 0)
#define EXP2(x) __builtin_amdgcn_exp2f(x)

static constexpr float kScale = 0.08838834764831845f;  // 1/sqrt(128)
static constexpr float kLog2e = 1.4426950408889634f;
static constexpr float kC1 = kScale * kLog2e;  // raw-score -> exp2 argument

// async global->LDS, 16B per lane; LDS dst is wave-uniform base + lane*16
__device__ __forceinline__ void lds_cp16(void* lds, const void* g) {
  __builtin_amdgcn_global_load_lds(
      (__attribute__((address_space(1))) void*)(uintptr_t)g,
      (__attribute__((address_space(3))) void*)(uintptr_t)lds, 16, 0, 0);
}

// Stage a [R rows x K cols] bf16 tile into chunked LDS: (r,k) -> (k>>5)*(R*32)+r*32+(k&31).
// Identity (verified): dst elem offset i*2048 + w*512 + l*8 == chunk*(R*32) + r*32 + c
// for the staged linear index -- holds for any K multiple of 32 at R=128.
template <int R, int K>
__device__ __forceinline__ void stage_tile(bf16_t* lds, const bf16_t* g, int ldg, int tid) {
  constexpr int TOT = R * K;
  constexpr int CH = R * 32;
  constexpr int ITERS = TOT / 2048;  // 256 threads * 8 elems
  const int wave = tid >> 6;
#pragma unroll
  for (int i = 0; i < ITERS; ++i) {
    int linear = i * 2048 + tid * 8;
    int chunk = linear / CH;
    int rem = linear % CH;
    int r = rem >> 5;
    int c = rem & 31;
    lds_cp16(lds + i * 2048 + wave * 512, g + r * ldg + chunk * 32 + c);
  }
}

__device__ __forceinline__ bf16x8 frag_ld(const bf16_t* lds_chunk, int row, int lane) {
  return *(const bf16x8*)(lds_chunk + row * 32 + ((lane >> 4) << 3));
}

// In-register P^T -> A-fragment transform (VERIFIED rounds 5-11; permlane16 variants both
// failed on HW -- do not revisit without a standalone probe).
// Input: pa = exp2'd P rows ms=0 (r=0..3), pb = ms=1; this lane = (quad, l15).
// Source layout: P[m=ms*16+quad*4+r][n=nsub*16+l15]. Output: A-frag bf16x8 with
// element jj = P[m=quad*8+jj][n=nsub*16+l15].
// After v_permlane32_swap(a,b): a=X0={a.lo,b.lo}, b=X1={a.hi,b.hi};
// word0 = hi16 ? swz16(X1) : X0 ; word2 = hi16 ? X1 : swz16(X0)  (same for Y from a1,b1).
__device__ __forceinline__ bf16x8 p_transpose(f32x4 pa, f32x4 pb, bool hi16) {
  uint32_t a0, a1, b0, b1;
  asm("v_cvt_pk_bf16_f32 %0, %1, %2" : "=v"(a0) : "v"(pa[0]), "v"(pa[1]));
  asm("v_cvt_pk_bf16_f32 %0, %1, %2" : "=v"(a1) : "v"(pa[2]), "v"(pa[3]));
  asm("v_cvt_pk_bf16_f32 %0, %1, %2" : "=v"(b0) : "v"(pb[0]), "v"(pb[1]));
  asm("v_cvt_pk_bf16_f32 %0, %1, %2" : "=v"(b1) : "v"(pb[2]), "v"(pb[3]));
  asm("v_permlane32_swap_b32 %0, %1" : "+v"(a0), "+v"(b0));  // a0=X0, b0=X1
  asm("v_permlane32_swap_b32 %0, %1" : "+v"(a1), "+v"(b1));  // a1=Y0, b1=Y1
  uint32_t sX0 = (uint32_t)__builtin_amdgcn_ds_swizzle((int)a0, 0x401F);  // lane^16
  uint32_t sX1 = (uint32_t)__builtin_amdgcn_ds_swizzle((int)b0, 0x401F);
  uint32_t sY0 = (uint32_t)__builtin_amdgcn_ds_swizzle((int)a1, 0x401F);
  uint32_t sY1 = (uint32_t)__builtin_amdgcn_ds_swizzle((int)b1, 0x401F);
  union {
    uint32_t u[4];
    bf16x8 v;
  } r;
  r.u[0] = hi16 ? sX1 : a0;
  r.u[1] = hi16 ? sY1 : a1;
  r.u[2] = hi16 ? b0 : sX0;
  r.u[3] = hi16 ? b1 : sY0;
  return r.v;
}

// ---------- elementwise f32 -> bf16 convert ----------
__global__ void cvt_kernel(const float* __restrict__ src, bf16_t* __restrict__ dst) {
  const int i = (blockIdx.x * 256 + threadIdx.x) * 4;
  float4 v = *(const float4*)&src[i];
  bf16x4 o;
  o[0] = (bf16_t)v.x;
  o[1] = (bf16_t)v.y;
  o[2] = (bf16_t)v.z;
  o[3] = (bf16_t)v.w;
  *(bf16x4*)&dst[i] = o;
}

// ---------- merged tiled transpose for Wq/Wk/Wv: f32 [8][1024][128] -> bf16 [8][128][1024]
// one launch, z = 0..23 selects (proj, head); R=1024, C=128 fixed.
__global__ void transpose_qkv_k(const float* __restrict__ Wq, const float* __restrict__ Wk,
                                const float* __restrict__ Wv, bf16_t* __restrict__ Wt) {
  __shared__ alignas(16) bf16_t tile[64][72];
  const int t = threadIdx.x;
  const int z = blockIdx.z;
  const int proj = z >> 3, mat = z & 7;
  const float* src = (proj == 0 ? Wq : proj == 1 ? Wk : Wv);
  const int R = 1024, C = 128;
  const int r0 = blockIdx.x * 64, c0 = blockIdx.y * 64;
  const float* s = src + (size_t)mat * R * C;
  bf16_t* d = Wt + (size_t)proj * 1048576 + (size_t)mat * R * C;
  const int rl = t >> 3, cl = (t & 7) * 8;
#pragma unroll
  for (int half = 0; half < 2; ++half) {
    const int r = r0 + rl + half * 32;
    float4 a = *(const float4*)&s[(size_t)r * C + c0 + cl];
    float4 b = *(const float4*)&s[(size_t)r * C + c0 + cl + 4];
    tile[cl + 0][rl + half * 32] = (bf16_t)a.x;
    tile[cl + 1][rl + half * 32] = (bf16_t)a.y;
    tile[cl + 2][rl + half * 32] = (bf16_t)a.z;
    tile[cl + 3][rl + half * 32] = (bf16_t)a.w;
    tile[cl + 4][rl + half * 32] = (bf16_t)b.x;
    tile[cl + 5][rl + half * 32] = (bf16_t)b.y;
    tile[cl + 6][rl + half * 32] = (bf16_t)b.z;
    tile[cl + 7][rl + half * 32] = (bf16_t)b.w;
  }
  __syncthreads();
  const int cl2 = t >> 3, rl2 = (t & 7) * 8;
  *(bf16x8*)&d[(size_t)(c0 + cl2) * R + r0 + rl2] = *(const bf16x8*)&tile[cl2][rl2];
  *(bf16x8*)&d[(size_t)(c0 + cl2 + 32) * R + r0 + rl2] = *(const bf16x8*)&tile[cl2 + 32][rl2];
}

// ---------- projections, writing fragment-major Qf/Kf/Vf directly ----------
// Qf/Kf: [h][nt(256)][ks(4)][lane(64)][8]  (frag = q[nt*16+l15][ks*32+quad*8+j])
// Vf:    [h][mb(128)][es(8)][lane(64)][8]  (frag = v[mb*32+quad*8+j][es*16+l15])
// BK=128 (was 64): barrier count 16 (vs 32) -- same verified stage_tile/frag_ld mapping,
// kk now spans 4 chunks. As/Bs 32KB each in loop; Ct[128][136] epilogue overlays.
__global__ __launch_bounds__(256, 2) void proj_kernel(const bf16_t* __restrict__ X,
                                                      const bf16_t* __restrict__ Wt,
                                                      const float* __restrict__ bq,
                                                      const float* __restrict__ bk,
                                                      const float* __restrict__ bv,
                                                      bf16_t* __restrict__ qkv) {
  __shared__ alignas(16) char smem[65536];  // As(32K)+Bs(32K) in loop; Ct[128][136] epilogue
  bf16_t* As = (bf16_t*)smem;
  bf16_t* Bs = (bf16_t*)(smem + 32768);
  const int t = threadIdx.x, lane = t & 63, w = t >> 6;
  const int l15 = lane & 15, quad = lane >> 4;
  const int ntile = blockIdx.x, mat = blockIdx.y;
  const bf16_t* a0 = X + (size_t)ntile * 128 * 1024;
  const bf16_t* b0 = Wt + (size_t)mat * 131072;
  f32x4 acc[4][4] = {};
  const int rb = (w >> 1) * 64, cb = (w & 1) * 64;
  for (int k0 = 0; k0 < 1024; k0 += 128) {
    stage_tile<128, 128>(As, a0 + k0, 1024, t);
    stage_tile<128, 128>(Bs, b0 + k0, 1024, t);
    __syncthreads();
#pragma unroll
    for (int kk = 0; kk < 4; ++kk) {
      bf16x8 af[4], bfr[4];
#pragma unroll
      for (int i = 0; i < 4; ++i) af[i] = frag_ld(As + kk * 4096, rb + i * 16 + l15, lane);
#pragma unroll
      for (int j = 0; j < 4; ++j) bfr[j] = frag_ld(Bs + kk * 4096, cb + j * 16 + l15, lane);
#pragma unroll
      for (int i = 0; i < 4; ++i)
#pragma unroll
        for (int j = 0; j < 4; ++j) acc[i][j] = MFMA_16x16x32(af[i], bfr[j], acc[i][j]);
    }
    __syncthreads();
  }
  const int proj = mat >> 3, h = mat & 7;
  const float* bias = (proj == 0 ? bq : proj == 1 ? bk : bv) + h * 128;
  bf16_t* Ct = (bf16_t*)smem;  // safe: loop ended with __syncthreads
  bf16_t* dst = qkv + (size_t)proj * 4194304 + (size_t)h * 524288;
  if (proj < 2) {
    // n-major bounce [n][e], pitch 136 (keeps 16B alignment, breaks pow2 stride)
#pragma unroll
    for (int i = 0; i < 4; ++i)
#pragma unroll
      for (int j = 0; j < 4; ++j) {
        const int e = cb + j * 16 + l15;
        const float bval = bias[e];
#pragma unroll
        for (int r = 0; r < 4; ++r)
          Ct[(rb + i * 16 + quad * 4 + r) * 136 + e] = (bf16_t)(acc[i][j][r] + bval);
      }
    __syncthreads();
#pragma unroll
    for (int u = 0; u < 2; ++u) {
      const int nt = w * 2 + u;
#pragma unroll
      for (int ks = 0; ks < 4; ++ks) {
        bf16x8 f = *(const bf16x8*)&Ct[(nt * 16 + l15) * 136 + ks * 32 + quad * 8];
        *(bf16x8*)&dst[(((size_t)(ntile * 8 + nt)) * 4 + ks) * 512 + lane * 8] = f;
      }
    }
  } else {
    // e-major bounce [e][m] (m = this block's n rows), b64 writes / b128 reads
#pragma unroll
    for (int i = 0; i < 4; ++i)
#pragma unroll
      for (int j = 0; j < 4; ++j) {
        const int e = cb + j * 16 + l15;
        const float bval = bias[e];
        bf16x4 pv;
#pragma unroll
        for (int r = 0; r < 4; ++r) pv[r] = (bf16_t)(acc[i][j][r] + bval);
        *(bf16x4*)&Ct[e * 136 + rb + i * 16 + quad * 4] = pv;
      }
    __syncthreads();
#pragma unroll
    for (int es = 0; es < 8; ++es) {
      bf16x8 f = *(const bf16x8*)&Ct[(es * 16 + l15) * 136 + w * 32 + quad * 8];
      *(bf16x8*)&dst[(((size_t)(ntile * 4 + w)) * 8 + es) * 512 + lane * 8] = f;
    }
  }
}

// ---------- pass A: l2c[h][m] = log2( sum_n exp2(c1 * q[n].k[m]) ) ----------
// grid (8 h, 64 mtile of 64m); kf resident (16 frags = 64 VGPR); rolling af stream.
__global__ __launch_bounds__(256, 2) void pass_a_kernel(const bf16_t* __restrict__ Qf,
                                                        const bf16_t* __restrict__ Kf,
                                                        float* __restrict__ l2c) {
  __shared__ alignas(16) float csred[4][64];
  const int t = threadIdx.x, lane = t & 63, w = t >> 6;
  const int l15 = lane & 15;
  const int h = blockIdx.x, mtile = blockIdx.y;
  const bf16_t* Qh = Qf + (size_t)h * 524288;
  const bf16_t* Kh = Kf + (size_t)h * 524288;
  bf16x8 kf[16];  // B-operand, 64m resident
#pragma unroll
  for (int mg = 0; mg < 4; ++mg)
#pragma unroll
    for (int ks = 0; ks < 4; ++ks)
      kf[mg * 4 + ks] = *(const bf16x8*)&Kh[((mtile * 4 + mg) * 4 + ks) * 512 + lane * 8];
  float cs[4] = {0.f, 0.f, 0.f, 0.f};
  uint32_t qo = w * 2048 + lane * 8;
  bf16x8 af[4];
#pragma unroll
  for (int ks = 0; ks < 4; ++ks) af[ks] = *(const bf16x8*)&Qh[qo + ks * 512];
  for (int it = 0; it < 64; ++it) {
    f32x4 c[4] = {};
#pragma unroll
    for (int ks = 0; ks < 4; ++ks)
#pragma unroll
      for (int mg = 0; mg < 4; ++mg) c[mg] = MFMA_16x16x32(af[ks], kf[mg * 4 + ks], c[mg]);
    qo += 8192;  // 4 tiles ahead (tail overreads next region: allocated, harmless)
#pragma unroll
    for (int ks = 0; ks < 4; ++ks) af[ks] = *(const bf16x8*)&Qh[qo + ks * 512];
#pragma unroll
    for (int mg = 0; mg < 4; ++mg)
#pragma unroll
      for (int r = 0; r < 4; ++r) cs[mg] += EXP2(c[mg][r] * kC1);
  }
#pragma unroll
  for (int mg = 0; mg < 4; ++mg) {
    cs[mg] += __shfl_xor(cs[mg], 16, 64);
    cs[mg] += __shfl_xor(cs[mg], 32, 64);
  }
  if (lane < 16) {
#pragma unroll
    for (int mg = 0; mg < 4; ++mg) csred[w][mg * 16 + lane] = cs[mg];
  }
  __syncthreads();
  if (t < 64)
    l2c[(size_t)h * 4096 + mtile * 64 + t] =
        __builtin_log2f(csred[0][t] + csred[1][t] + csred[2][t] + csred[3][t]);
}

// ---------- pass B: z[n][e] = sum_m exp2(c1*s - l2c[m]) * v[m][e]; sigmoid; store f32 ----------
// Round-5/11 schedule (best verified): grid (8 h, 32 ntile of 128n), 512 threads (8 waves),
// npar = w&3, mpar = w>>2. K direct from L2 with it+2 register prefetch; V in 4-iter windows
// (64KB dbuf = 128KB LDS, one barrier per 4 iters); T15 QK(it+1) pipeline; T12 in-register
// P transpose (verified ds_swizzle form).
__global__ __launch_bounds__(512, 2) void pass_b_kernel(const bf16_t* __restrict__ Qf,
                                                        const bf16_t* __restrict__ Kf,
                                                        const bf16_t* __restrict__ Vf,
                                                        const float* __restrict__ l2c,
                                                        float* __restrict__ out) {
  __shared__ alignas(16) char smem[131072];
  const int t = threadIdx.x, lane = t & 63, w = t >> 6;
  const int quad = lane >> 4, l15 = lane & 15;
  const bool hi16 = (lane & 16) != 0;
  const int npar = w & 3, mpar = w >> 2;
  const int h = blockIdx.x, ntile = blockIdx.y;
  const bf16_t* Kh = Kf + (size_t)h * 524288;  // head stride = 524288 ELEMENTS (1 MB)
  const char* VhB = (const char*)(Vf + (size_t)h * 524288);
  const bf16_t* Qh = Qf + (size_t)h * 524288;
  const float* lb = l2c + (size_t)h * 4096;

  // stage V window 0 (iters 0..3, 64KB) into buf 0: wave w stages [w*8KB, (w+1)*8KB)
#pragma unroll
  for (int j = 0; j < 8; ++j) {
    const int off = (w * 8 + j) * 1024;
    lds_cp16(smem + off, VhB + off + lane * 16);
  }
  // q B-operand fragments (col n = this wave's 32n), resident
  bf16x8 qf[2][4];
#pragma unroll
  for (int nsub = 0; nsub < 2; ++nsub)
#pragma unroll
    for (int ks = 0; ks < 4; ++ks)
      qf[nsub][ks] =
          *(const bf16x8*)&Qh[((ntile * 8 + npar * 2 + nsub) * 4 + ks) * 512 + lane * 8];
  // k A-fragments for it=0, direct from global (L2)
  bf16x8 kf[8];
  {
    const bf16_t* kg = Kh + mpar * 4096;
#pragma unroll
    for (int u = 0; u < 8; ++u) kf[u] = *(const bf16x8*)&kg[u * 512 + lane * 8];
  }
  // l2c guide values for it=0, register-prefetched
  f32x4 gc0 = *(const f32x4*)&lb[mpar * 32 + quad * 4];
  f32x4 gc1 = *(const f32x4*)&lb[mpar * 32 + 16 + quad * 4];
  f32x4 zacc[2][8] = {};
  __syncthreads();  // full drain once (prologue staging + qf + kf + g)

  // pipeline prologue: QK(0) into ccp; issue kf(1)
  f32x4 ccp[2][2] = {};
  __builtin_amdgcn_s_setprio(1);
#pragma unroll
  for (int ks = 0; ks < 4; ++ks)
#pragma unroll
    for (int ms = 0; ms < 2; ++ms)
#pragma unroll
      for (int nsub = 0; nsub < 2; ++nsub)
        ccp[ms][nsub] = MFMA_16x16x32(kf[ms * 4 + ks], qf[nsub][ks], ccp[ms][nsub]);
  __builtin_amdgcn_s_setprio(0);
  {
    const bf16_t* kg = Kh + 8192 + mpar * 4096;
#pragma unroll
    for (int u = 0; u < 8; ++u) kf[u] = *(const bf16x8*)&kg[u * 512 + lane * 8];
  }

  for (int wnd = 0; wnd < 16; ++wnd) {
    const int cur = wnd & 1;
    // stage next window's V (64KB) into the other buffer; oldest 8 vmem ops of this window
    if (wnd < 15) {
      char* vdst = smem + (cur ^ 1) * 65536;
      const char* vsrc = VhB + (size_t)(wnd + 1) * 65536;
#pragma unroll
      for (int j = 0; j < 8; ++j) {
        const int off = (w * 8 + j) * 1024;
        lds_cp16(vdst + off, vsrc + off + lane * 16);
      }
    }
    __builtin_amdgcn_sched_barrier(0);  // pin: staging stays first in issue order
#pragma unroll
    for (int sub = 0; sub < 4; ++sub) {
      const int it = wnd * 4 + sub;
      // ---- QK for it+1 (kf holds kf(it+1); register-only, overlaps finish(it)) ----
      f32x4 ccn[2][2] = {};
      __builtin_amdgcn_s_setprio(1);
#pragma unroll
      for (int ks = 0; ks < 4; ++ks)
#pragma unroll
        for (int ms = 0; ms < 2; ++ms)
#pragma unroll
          for (int nsub = 0; nsub < 2; ++nsub)
            ccn[ms][nsub] = MFMA_16x16x32(kf[ms * 4 + ks], qf[nsub][ks], ccn[ms][nsub]);
      __builtin_amdgcn_s_setprio(0);
      // issue kf(it+2) into the just-freed regs (WAR-safe; in flight across the barrier;
      // tail overreads into adjacent Vf region: allocated, harmless)
      {
        const bf16_t* kg = Kh + (size_t)(it + 2) * 8192 + mpar * 4096;
#pragma unroll
        for (int u = 0; u < 8; ++u) kf[u] = *(const bf16x8*)&kg[u * 512 + lane * 8];
      }
      // ---- finish it: exp2 + in-register transpose (verified ds_swizzle form) ----
      bf16x8 pf[2];
#pragma unroll
      for (int nsub = 0; nsub < 2; ++nsub) {
        f32x4 pa, pb;
#pragma unroll
        for (int r = 0; r < 4; ++r) pa[r] = EXP2(ccp[0][nsub][r] * kC1 - gc0[r]);
#pragma unroll
        for (int r = 0; r < 4; ++r) pb[r] = EXP2(ccp[1][nsub][r] * kC1 - gc1[r]);
        pf[nsub] = p_transpose(pa, pb, hi16);
      }
      // prefetch g for it+1 (clamped at the tail)
      {
        const int stn = (it < 63 ? it + 1 : 63) * 2 + mpar;
        gc0 = *(const f32x4*)&lb[stn * 32 + quad * 4];
        gc1 = *(const f32x4*)&lb[stn * 32 + 16 + quad * 4];
      }
      // ---- PV(it) from this window's V buffer ----
      const bf16_t* vbase = (const bf16_t*)(smem + cur * 65536 + sub * 16384) + mpar * 4096;
      __builtin_amdgcn_s_setprio(1);
#pragma unroll
      for (int es = 0; es < 8; ++es) {
        bf16x8 vf = *(const bf16x8*)&vbase[es * 512 + lane * 8];
#pragma unroll
        for (int nsub = 0; nsub < 2; ++nsub)
          zacc[nsub][es] = MFMA_16x16x32(pf[nsub], vf, zacc[nsub][es]);
      }
      __builtin_amdgcn_s_setprio(0);
      // carry the pipeline register
#pragma unroll
      for (int ms = 0; ms < 2; ++ms)
#pragma unroll
        for (int nsub = 0; nsub < 2; ++nsub) ccp[ms][nsub] = ccn[ms][nsub];
    }
    // window-end: counted drain (staging ops are the oldest), raw barrier
    asm volatile("s_waitcnt vmcnt(8)" ::: "memory");
    __builtin_amdgcn_s_barrier();
  }
  // epilogue: merge mpar pairs via LDS (overlays V buf 0; all waves barrier-synced), sigmoid
  float* red = (float*)smem;  // [npar][nsub*8+es][lane*4] = 16KB per npar
  if (mpar == 1) {
#pragma unroll
    for (int nsub = 0; nsub < 2; ++nsub)
#pragma unroll
      for (int es = 0; es < 8; ++es)
        *(f32x4*)&red[npar * 4096 + (nsub * 8 + es) * 256 + lane * 4] = zacc[nsub][es];
  }
  __syncthreads();
  if (mpar == 0) {
#pragma unroll
    for (int nsub = 0; nsub < 2; ++nsub) {
#pragma unroll
      for (int es = 0; es < 8; ++es) {
        f32x4 o = *(const f32x4*)&red[npar * 4096 + (nsub * 8 + es) * 256 + lane * 4];
        const int e = es * 16 + l15;
#pragma unroll
        for (int r = 0; r < 4; ++r) {
          const int n = ntile * 128 + npar * 32 + nsub * 16 + quad * 4 + r;
          const float z = zacc[nsub][es][r] + o[r];
          out[(size_t)n * 1024 + h * 128 + e] = 1.f / (1.f + EXP2(-z * kLog2e));
        }
      }
    }
  }
}

extern "C" void kernel_launch(void* const* d_in, const int* in_sizes, int n_in, void* d_out,
                              int out_size, void* d_ws, size_t ws_size, hipStream_t stream) {
  (void)in_sizes;
  (void)n_in;
  (void)out_size;
  (void)ws_size;
  const float* X = (const float*)d_in[0];
  const float* Wq = (const float*)d_in[1];
  const float* bq = (const float*)d_in[2];
  const float* Wk = (const float*)d_in[3];
  const float* bk = (const float*)d_in[4];
  const float* Wv = (const float*)d_in[5];
  const float* bv = (const float*)d_in[6];
  float* out = (float*)d_out;
  char* ws = (char*)d_ws;
  // byte layout (39.98 MB):
  //  [0,8M): Qf   [8M,16M): Kf   [16M,24M): Vf
  //  [24M,32M): Xb (cvt out, proj in)
  //  [32M,38M): Wt (dead after proj)
  //  [39845888,+128K): l2c
  bf16_t* Qf = (bf16_t*)(ws);
  bf16_t* Kf = (bf16_t*)(ws + 8388608);
  bf16_t* Vf = (bf16_t*)(ws + 16777216);
  bf16_t* Xb = (bf16_t*)(ws + 25165824);
  bf16_t* Wt = (bf16_t*)(ws + 33554432);
  float* l2c = (float*)(ws + 39845888);

  cvt_kernel<<<4096, 256, 0, stream>>>(X, Xb);
  transpose_qkv_k<<<dim3(16, 2, 24), 256, 0, stream>>>(Wq, Wk, Wv, Wt);
  proj_kernel<<<dim3(32, 24), 256, 0, stream>>>(Xb, Wt, bq, bk, bv, Qf);
  pass_a_kernel<<<dim3(8, 64), 256, 0, stream>>>(Qf, Kf, l2c);
  pass_b_kernel<<<dim3(8, 32), 512, 0, stream>>>(Qf, Kf, Vf, l2c, out);
}

// Round 15
// 236.143 us; speedup vs baseline: 1.0085x; 1.0085x over previous
//
#include <hip/hip_runtime.h>
#include <hip/hip_bf16.h>
#include <stdint.h>

typedef __bf16 bf16_t;
typedef __bf16 bf16x4 __attribute__((ext_vector_type(4)));
typedef __bf16 bf16x8 __attribute__((ext_vector_type(8)));
typedef float f32x4 __attribute__((ext_vector_type(4)));

#define MFMA_16x16x32(A, B, C) __builtin_amdgcn_mfma_f32_16x16x32_bf16(A, B, C, 0, 0, 0)
#define EXP2(x) __builtin_amdgcn_exp2f(x)

static constexpr float kScale = 0.08838834764831845f;  // 1/sqrt(128)
static constexpr float kLog2e = 1.4426950408889634f;
static constexpr float kC1 = kScale * kLog2e;  // raw-score -> exp2 argument

// async global->LDS, 16B per lane; LDS dst is wave-uniform base + lane*16
__device__ __forceinline__ void lds_cp16(void* lds, const void* g) {
  __builtin_amdgcn_global_load_lds(
      (__attribute__((address_space(1))) void*)(uintptr_t)g,
      (__attribute__((address_space(3))) void*)(uintptr_t)lds, 16, 0, 0);
}

// Stage a [R rows x K cols] bf16 tile into chunked LDS: (r,k) -> (k>>5)*(R*32)+r*32+(k&31).
template <int R, int K>
__device__ __forceinline__ void stage_tile(bf16_t* lds, const bf16_t* g, int ldg, int tid) {
  constexpr int TOT = R * K;
  constexpr int CH = R * 32;
  constexpr int ITERS = TOT / 2048;  // 256 threads * 8 elems
  const int wave = tid >> 6;
#pragma unroll
  for (int i = 0; i < ITERS; ++i) {
    int linear = i * 2048 + tid * 8;
    int chunk = linear / CH;
    int rem = linear % CH;
    int r = rem >> 5;
    int c = rem & 31;
    lds_cp16(lds + i * 2048 + wave * 512, g + r * ldg + chunk * 32 + c);
  }
}

__device__ __forceinline__ bf16x8 frag_ld(const bf16_t* lds_chunk, int row, int lane) {
  return *(const bf16x8*)(lds_chunk + row * 32 + ((lane >> 4) << 3));
}

// In-register P^T -> A-fragment transform (VERIFIED rounds 5-14; permlane16 variants both
// failed on HW -- do not revisit without a standalone probe).
// Input: pa = exp2'd P rows ms=0 (r=0..3), pb = ms=1; this lane = (quad, l15).
// Source layout: P[m=ms*16+quad*4+r][n=nsub*16+l15]. Output: A-frag bf16x8 with
// element jj = P[m=quad*8+jj][n=nsub*16+l15].
// After v_permlane32_swap(a,b): a=X0={a.lo,b.lo}, b=X1={a.hi,b.hi};
// word0 = hi16 ? swz16(X1) : X0 ; word2 = hi16 ? X1 : swz16(X0)  (same for Y from a1,b1).
__device__ __forceinline__ bf16x8 p_transpose(f32x4 pa, f32x4 pb, bool hi16) {
  uint32_t a0, a1, b0, b1;
  asm("v_cvt_pk_bf16_f32 %0, %1, %2" : "=v"(a0) : "v"(pa[0]), "v"(pa[1]));
  asm("v_cvt_pk_bf16_f32 %0, %1, %2" : "=v"(a1) : "v"(pa[2]), "v"(pa[3]));
  asm("v_cvt_pk_bf16_f32 %0, %1, %2" : "=v"(b0) : "v"(pb[0]), "v"(pb[1]));
  asm("v_cvt_pk_bf16_f32 %0, %1, %2" : "=v"(b1) : "v"(pb[2]), "v"(pb[3]));
  asm("v_permlane32_swap_b32 %0, %1" : "+v"(a0), "+v"(b0));  // a0=X0, b0=X1
  asm("v_permlane32_swap_b32 %0, %1" : "+v"(a1), "+v"(b1));  // a1=Y0, b1=Y1
  uint32_t sX0 = (uint32_t)__builtin_amdgcn_ds_swizzle((int)a0, 0x401F);  // lane^16
  uint32_t sX1 = (uint32_t)__builtin_amdgcn_ds_swizzle((int)b0, 0x401F);
  uint32_t sY0 = (uint32_t)__builtin_amdgcn_ds_swizzle((int)a1, 0x401F);
  uint32_t sY1 = (uint32_t)__builtin_amdgcn_ds_swizzle((int)b1, 0x401F);
  union {
    uint32_t u[4];
    bf16x8 v;
  } r;
  r.u[0] = hi16 ? sX1 : a0;
  r.u[1] = hi16 ? sY1 : a1;
  r.u[2] = hi16 ? b0 : sX0;
  r.u[3] = hi16 ? b1 : sY0;
  return r.v;
}

// ---------- elementwise f32 -> bf16 convert ----------
__global__ void cvt_kernel(const float* __restrict__ src, bf16_t* __restrict__ dst) {
  const int i = (blockIdx.x * 256 + threadIdx.x) * 4;
  float4 v = *(const float4*)&src[i];
  bf16x4 o;
  o[0] = (bf16_t)v.x;
  o[1] = (bf16_t)v.y;
  o[2] = (bf16_t)v.z;
  o[3] = (bf16_t)v.w;
  *(bf16x4*)&dst[i] = o;
}

// ---------- merged tiled transpose for Wq/Wk/Wv: f32 [8][1024][128] -> bf16 [8][128][1024]
__global__ void transpose_qkv_k(const float* __restrict__ Wq, const float* __restrict__ Wk,
                                const float* __restrict__ Wv, bf16_t* __restrict__ Wt) {
  __shared__ alignas(16) bf16_t tile[64][72];
  const int t = threadIdx.x;
  const int z = blockIdx.z;
  const int proj = z >> 3, mat = z & 7;
  const float* src = (proj == 0 ? Wq : proj == 1 ? Wk : Wv);
  const int R = 1024, C = 128;
  const int r0 = blockIdx.x * 64, c0 = blockIdx.y * 64;
  const float* s = src + (size_t)mat * R * C;
  bf16_t* d = Wt + (size_t)proj * 1048576 + (size_t)mat * R * C;
  const int rl = t >> 3, cl = (t & 7) * 8;
#pragma unroll
  for (int half = 0; half < 2; ++half) {
    const int r = r0 + rl + half * 32;
    float4 a = *(const float4*)&s[(size_t)r * C + c0 + cl];
    float4 b = *(const float4*)&s[(size_t)r * C + c0 + cl + 4];
    tile[cl + 0][rl + half * 32] = (bf16_t)a.x;
    tile[cl + 1][rl + half * 32] = (bf16_t)a.y;
    tile[cl + 2][rl + half * 32] = (bf16_t)a.z;
    tile[cl + 3][rl + half * 32] = (bf16_t)a.w;
    tile[cl + 4][rl + half * 32] = (bf16_t)b.x;
    tile[cl + 5][rl + half * 32] = (bf16_t)b.y;
    tile[cl + 6][rl + half * 32] = (bf16_t)b.z;
    tile[cl + 7][rl + half * 32] = (bf16_t)b.w;
  }
  __syncthreads();
  const int cl2 = t >> 3, rl2 = (t & 7) * 8;
  *(bf16x8*)&d[(size_t)(c0 + cl2) * R + r0 + rl2] = *(const bf16x8*)&tile[cl2][rl2];
  *(bf16x8*)&d[(size_t)(c0 + cl2 + 32) * R + r0 + rl2] = *(const bf16x8*)&tile[cl2 + 32][rl2];
}

// ---------- projections (round-11 verified BK=64 form) ----------
// Qf/Kf: [h][nt(256)][ks(4)][lane(64)][8]; Vf: [h][mb(128)][es(8)][lane(64)][8]
__global__ __launch_bounds__(256, 2) void proj_kernel(const bf16_t* __restrict__ X,
                                                      const bf16_t* __restrict__ Wt,
                                                      const float* __restrict__ bq,
                                                      const float* __restrict__ bk,
                                                      const float* __restrict__ bv,
                                                      bf16_t* __restrict__ qkv) {
  __shared__ alignas(16) char smem[34816];  // As(16K)+Bs(16K) in loop; Ct[128][136] epilogue
  bf16_t* As = (bf16_t*)smem;
  bf16_t* Bs = (bf16_t*)(smem + 16384);
  const int t = threadIdx.x, lane = t & 63, w = t >> 6;
  const int l15 = lane & 15, quad = lane >> 4;
  const int ntile = blockIdx.x, mat = blockIdx.y;
  const bf16_t* a0 = X + (size_t)ntile * 128 * 1024;
  const bf16_t* b0 = Wt + (size_t)mat * 131072;
  f32x4 acc[4][4] = {};
  const int rb = (w >> 1) * 64, cb = (w & 1) * 64;
  for (int k0 = 0; k0 < 1024; k0 += 64) {
    stage_tile<128, 64>(As, a0 + k0, 1024, t);
    stage_tile<128, 64>(Bs, b0 + k0, 1024, t);
    __syncthreads();
#pragma unroll
    for (int kk = 0; kk < 2; ++kk) {
      bf16x8 af[4], bfr[4];
#pragma unroll
      for (int i = 0; i < 4; ++i) af[i] = frag_ld(As + kk * 4096, rb + i * 16 + l15, lane);
#pragma unroll
      for (int j = 0; j < 4; ++j) bfr[j] = frag_ld(Bs + kk * 4096, cb + j * 16 + l15, lane);
#pragma unroll
      for (int i = 0; i < 4; ++i)
#pragma unroll
        for (int j = 0; j < 4; ++j) acc[i][j] = MFMA_16x16x32(af[i], bfr[j], acc[i][j]);
    }
    __syncthreads();
  }
  const int proj = mat >> 3, h = mat & 7;
  const float* bias = (proj == 0 ? bq : proj == 1 ? bk : bv) + h * 128;
  bf16_t* Ct = (bf16_t*)smem;  // safe: loop ended with __syncthreads
  bf16_t* dst = qkv + (size_t)proj * 4194304 + (size_t)h * 524288;
  if (proj < 2) {
    // n-major bounce [n][e], pitch 136 (keeps 16B alignment, breaks pow2 stride)
#pragma unroll
    for (int i = 0; i < 4; ++i)
#pragma unroll
      for (int j = 0; j < 4; ++j) {
        const int e = cb + j * 16 + l15;
        const float bval = bias[e];
#pragma unroll
        for (int r = 0; r < 4; ++r)
          Ct[(rb + i * 16 + quad * 4 + r) * 136 + e] = (bf16_t)(acc[i][j][r] + bval);
      }
    __syncthreads();
#pragma unroll
    for (int u = 0; u < 2; ++u) {
      const int nt = w * 2 + u;
#pragma unroll
      for (int ks = 0; ks < 4; ++ks) {
        bf16x8 f = *(const bf16x8*)&Ct[(nt * 16 + l15) * 136 + ks * 32 + quad * 8];
        *(bf16x8*)&dst[(((size_t)(ntile * 8 + nt)) * 4 + ks) * 512 + lane * 8] = f;
      }
    }
  } else {
    // e-major bounce [e][m] (m = this block's n rows), b64 writes / b128 reads
#pragma unroll
    for (int i = 0; i < 4; ++i)
#pragma unroll
      for (int j = 0; j < 4; ++j) {
        const int e = cb + j * 16 + l15;
        const float bval = bias[e];
        bf16x4 pv;
#pragma unroll
        for (int r = 0; r < 4; ++r) pv[r] = (bf16_t)(acc[i][j][r] + bval);
        *(bf16x4*)&Ct[e * 136 + rb + i * 16 + quad * 4] = pv;
      }
    __syncthreads();
#pragma unroll
    for (int es = 0; es < 8; ++es) {
      bf16x8 f = *(const bf16x8*)&Ct[(es * 16 + l15) * 136 + w * 32 + quad * 8];
      *(bf16x8*)&dst[(((size_t)(ntile * 4 + w)) * 8 + es) * 512 + lane * 8] = f;
    }
  }
}

// ---------- pass A: l2c[h][m] = log2( sum_n exp2(c1 * q[n].k[m]) ) ----------
__global__ __launch_bounds__(256, 2) void pass_a_kernel(const bf16_t* __restrict__ Qf,
                                                        const bf16_t* __restrict__ Kf,
                                                        float* __restrict__ l2c) {
  __shared__ alignas(16) float csred[4][64];
  const int t = threadIdx.x, lane = t & 63, w = t >> 6;
  const int l15 = lane & 15;
  const int h = blockIdx.x, mtile = blockIdx.y;
  const bf16_t* Qh = Qf + (size_t)h * 524288;
  const bf16_t* Kh = Kf + (size_t)h * 524288;
  bf16x8 kf[16];  // B-operand, 64m resident
#pragma unroll
  for (int mg = 0; mg < 4; ++mg)
#pragma unroll
    for (int ks = 0; ks < 4; ++ks)
      kf[mg * 4 + ks] = *(const bf16x8*)&Kh[((mtile * 4 + mg) * 4 + ks) * 512 + lane * 8];
  float cs[4] = {0.f, 0.f, 0.f, 0.f};
  uint32_t qo = w * 2048 + lane * 8;
  bf16x8 af[4];
#pragma unroll
  for (int ks = 0; ks < 4; ++ks) af[ks] = *(const bf16x8*)&Qh[qo + ks * 512];
  for (int it = 0; it < 64; ++it) {
    f32x4 c[4] = {};
#pragma unroll
    for (int ks = 0; ks < 4; ++ks)
#pragma unroll
      for (int mg = 0; mg < 4; ++mg) c[mg] = MFMA_16x16x32(af[ks], kf[mg * 4 + ks], c[mg]);
    qo += 8192;  // 4 tiles ahead (tail overreads next region: allocated, harmless)
#pragma unroll
    for (int ks = 0; ks < 4; ++ks) af[ks] = *(const bf16x8*)&Qh[qo + ks * 512];
#pragma unroll
    for (int mg = 0; mg < 4; ++mg)
#pragma unroll
      for (int r = 0; r < 4; ++r) cs[mg] += EXP2(c[mg][r] * kC1);
  }
#pragma unroll
  for (int mg = 0; mg < 4; ++mg) {
    cs[mg] += __shfl_xor(cs[mg], 16, 64);
    cs[mg] += __shfl_xor(cs[mg], 32, 64);
  }
  if (lane < 16) {
#pragma unroll
    for (int mg = 0; mg < 4; ++mg) csred[w][mg * 16 + lane] = cs[mg];
  }
  __syncthreads();
  if (t < 64)
    l2c[(size_t)h * 4096 + mtile * 64 + t] =
        __builtin_log2f(csred[0][t] + csred[1][t] + csred[2][t] + csred[3][t]);
}

// ---------- pass B: z[n][e] = sum_m exp2(c1*s - l2c[m]) * v[m][e]; sigmoid; store f32 ----------
// BARRIER-FREE main loop: both K and V read directly from L2 (frag-major; head h resident
// in XCD-h L2; per-iter K+V working set 32KB = L1-sized, so the 4 npar-duplicate waves are
// largely L1-served). V mapping derived from the verified LDS-staging identity:
// old LDS read == Vh[it*8192 + mpar*4096 + es*512 + lane*8]. No staging, no vmcnt, no
// main-loop s_barrier: 8 waves drift freely (max TLP in the measured latency-bound regime).
// V(it) loads issued at iter-top into registers (32 VGPR), hidden under QK+exp2+transform.
// LDS = 64KB epilogue reduction only.
__global__ __launch_bounds__(512, 2) void pass_b_kernel(const bf16_t* __restrict__ Qf,
                                                        const bf16_t* __restrict__ Kf,
                                                        const bf16_t* __restrict__ Vf,
                                                        const float* __restrict__ l2c,
                                                        float* __restrict__ out) {
  __shared__ alignas(16) char smem[65536];
  const int t = threadIdx.x, lane = t & 63, w = t >> 6;
  const int quad = lane >> 4, l15 = lane & 15;
  const bool hi16 = (lane & 16) != 0;
  const int npar = w & 3, mpar = w >> 2;
  const int h = blockIdx.x, ntile = blockIdx.y;
  const bf16_t* Kh = Kf + (size_t)h * 524288;  // head stride = 524288 ELEMENTS (1 MB)
  const bf16_t* Vh = Vf + (size_t)h * 524288;
  const bf16_t* Qh = Qf + (size_t)h * 524288;
  const float* lb = l2c + (size_t)h * 4096;

  // q B-operand fragments (col n = this wave's 32n), resident
  bf16x8 qf[2][4];
#pragma unroll
  for (int nsub = 0; nsub < 2; ++nsub)
#pragma unroll
    for (int ks = 0; ks < 4; ++ks)
      qf[nsub][ks] =
          *(const bf16x8*)&Qh[((ntile * 8 + npar * 2 + nsub) * 4 + ks) * 512 + lane * 8];
  // k A-fragments for it=0, direct from global (L2)
  bf16x8 kf[8];
  {
    const bf16_t* kg = Kh + mpar * 4096;
#pragma unroll
    for (int u = 0; u < 8; ++u) kf[u] = *(const bf16x8*)&kg[u * 512 + lane * 8];
  }
  // l2c guide values for it=0, register-prefetched
  f32x4 gc0 = *(const f32x4*)&lb[mpar * 32 + quad * 4];
  f32x4 gc1 = *(const f32x4*)&lb[mpar * 32 + 16 + quad * 4];
  f32x4 zacc[2][8] = {};

  // pipeline prologue: QK(0) into ccp; issue kf(1)
  f32x4 ccp[2][2] = {};
  __builtin_amdgcn_s_setprio(1);
#pragma unroll
  for (int ks = 0; ks < 4; ++ks)
#pragma unroll
    for (int ms = 0; ms < 2; ++ms)
#pragma unroll
      for (int nsub = 0; nsub < 2; ++nsub)
        ccp[ms][nsub] = MFMA_16x16x32(kf[ms * 4 + ks], qf[nsub][ks], ccp[ms][nsub]);
  __builtin_amdgcn_s_setprio(0);
  {
    const bf16_t* kg = Kh + 8192 + mpar * 4096;
#pragma unroll
    for (int u = 0; u < 8; ++u) kf[u] = *(const bf16x8*)&kg[u * 512 + lane * 8];
  }

  for (int it = 0; it < 64; ++it) {
    // issue V(it) loads first (independent; L2 latency hides under QK+exp2+transform)
    bf16x8 vfr[8];
    {
      const bf16_t* vg = Vh + (size_t)it * 8192 + mpar * 4096;
#pragma unroll
      for (int es = 0; es < 8; ++es) vfr[es] = *(const bf16x8*)&vg[es * 512 + lane * 8];
    }
    // ---- QK for it+1 (kf holds kf(it+1); register-only, overlaps finish(it)) ----
    f32x4 ccn[2][2] = {};
    __builtin_amdgcn_s_setprio(1);
#pragma unroll
    for (int ks = 0; ks < 4; ++ks)
#pragma unroll
      for (int ms = 0; ms < 2; ++ms)
#pragma unroll
        for (int nsub = 0; nsub < 2; ++nsub)
          ccn[ms][nsub] = MFMA_16x16x32(kf[ms * 4 + ks], qf[nsub][ks], ccn[ms][nsub]);
    __builtin_amdgcn_s_setprio(0);
    // issue kf(it+2) into the just-freed regs (WAR-safe; tail overreads into adjacent
    // Vf region: allocated, harmless)
    {
      const bf16_t* kg = Kh + (size_t)(it + 2) * 8192 + mpar * 4096;
#pragma unroll
      for (int u = 0; u < 8; ++u) kf[u] = *(const bf16x8*)&kg[u * 512 + lane * 8];
    }
    // ---- finish it: exp2 + in-register transpose (verified ds_swizzle form) ----
    bf16x8 pf[2];
#pragma unroll
    for (int nsub = 0; nsub < 2; ++nsub) {
      f32x4 pa, pb;
#pragma unroll
      for (int r = 0; r < 4; ++r) pa[r] = EXP2(ccp[0][nsub][r] * kC1 - gc0[r]);
#pragma unroll
      for (int r = 0; r < 4; ++r) pb[r] = EXP2(ccp[1][nsub][r] * kC1 - gc1[r]);
      pf[nsub] = p_transpose(pa, pb, hi16);
    }
    // prefetch g for it+1 (clamped at the tail)
    {
      const int stn = (it < 63 ? it + 1 : 63) * 2 + mpar;
      gc0 = *(const f32x4*)&lb[stn * 32 + quad * 4];
      gc1 = *(const f32x4*)&lb[stn * 32 + 16 + quad * 4];
    }
    // ---- PV(it) from registers ----
    __builtin_amdgcn_s_setprio(1);
#pragma unroll
    for (int es = 0; es < 8; ++es) {
#pragma unroll
      for (int nsub = 0; nsub < 2; ++nsub)
        zacc[nsub][es] = MFMA_16x16x32(pf[nsub], vfr[es], zacc[nsub][es]);
    }
    __builtin_amdgcn_s_setprio(0);
    // carry the pipeline register
#pragma unroll
    for (int ms = 0; ms < 2; ++ms)
#pragma unroll
      for (int nsub = 0; nsub < 2; ++nsub) ccp[ms][nsub] = ccn[ms][nsub];
  }
  // epilogue: merge mpar pairs via LDS, sigmoid, store f32
  float* red = (float*)smem;  // [npar][nsub*8+es][lane*4] = 16KB per npar
  if (mpar == 1) {
#pragma unroll
    for (int nsub = 0; nsub < 2; ++nsub)
#pragma unroll
      for (int es = 0; es < 8; ++es)
        *(f32x4*)&red[npar * 4096 + (nsub * 8 + es) * 256 + lane * 4] = zacc[nsub][es];
  }
  __syncthreads();
  if (mpar == 0) {
#pragma unroll
    for (int nsub = 0; nsub < 2; ++nsub) {
#pragma unroll
      for (int es = 0; es < 8; ++es) {
        f32x4 o = *(const f32x4*)&red[npar * 4096 + (nsub * 8 + es) * 256 + lane * 4];
        const int e = es * 16 + l15;
#pragma unroll
        for (int r = 0; r < 4; ++r) {
          const int n = ntile * 128 + npar * 32 + nsub * 16 + quad * 4 + r;
          const float z = zacc[nsub][es][r] + o[r];
          out[(size_t)n * 1024 + h * 128 + e] = 1.f / (1.f + EXP2(-z * kLog2e));
        }
      }
    }
  }
}

extern "C" void kernel_launch(void* const* d_in, const int* in_sizes, int n_in, void* d_out,
                              int out_size, void* d_ws, size_t ws_size, hipStream_t stream) {
  (void)in_sizes;
  (void)n_in;
  (void)out_size;
  (void)ws_size;
  const float* X = (const float*)d_in[0];
  const float* Wq = (const float*)d_in[1];
  const float* bq = (const float*)d_in[2];
  const float* Wk = (const float*)d_in[3];
  const float* bk = (const float*)d_in[4];
  const float* Wv = (const float*)d_in[5];
  const float* bv = (const float*)d_in[6];
  float* out = (float*)d_out;
  char* ws = (char*)d_ws;
  // byte layout (39.98 MB):
  //  [0,8M): Qf   [8M,16M): Kf   [16M,24M): Vf
  //  [24M,32M): Xb (cvt out, proj in)
  //  [32M,38M): Wt (dead after proj)
  //  [39845888,+128K): l2c
  bf16_t* Qf = (bf16_t*)(ws);
  bf16_t* Kf = (bf16_t*)(ws + 8388608);
  bf16_t* Vf = (bf16_t*)(ws + 16777216);
  bf16_t* Xb = (bf16_t*)(ws + 25165824);
  bf16_t* Wt = (bf16_t*)(ws + 33554432);
  float* l2c = (float*)(ws + 39845888);

  cvt_kernel<<<4096, 256, 0, stream>>>(X, Xb);
  transpose_qkv_k<<<dim3(16, 2, 24), 256, 0, stream>>>(Wq, Wk, Wv, Wt);
  proj_kernel<<<dim3(32, 24), 256, 0, stream>>>(Xb, Wt, bq, bk, bv, Qf);
  pass_a_kernel<<<dim3(8, 64), 256, 0, stream>>>(Qf, Kf, l2c);
  pass_b_kernel<<<dim3(8, 32), 512, 0, stream>>>(Qf, Kf, Vf, l2c, out);
}

// Round 17
// 234.414 us; speedup vs baseline: 1.0159x; 1.0074x over previous
//
#include <hip/hip_runtime.h>
#include <hip/hip_bf16.h>
#include <stdint.h>

typedef __bf16 bf16_t;
typedef __bf16 bf16x4 __attribute__((ext_vector_type(4)));
typedef __bf16 bf16x8 __attribute__((ext_vector_type(8)));
typedef float f32x4 __attribute__((ext_vector_type(4)));

#define MFMA_16x16x32(A, B, C) __builtin_amdgcn_mfma_f32_16x16x32_bf16(A, B, C, 0, 0, 0)
#define EXP2(x) __builtin_amdgcn_exp2f(x)

static constexpr float kScale = 0.08838834764831845f;  // 1/sqrt(128)
static constexpr float kLog2e = 1.4426950408889634f;
static constexpr float kC1 = kScale * kLog2e;  // raw-score -> exp2 argument

// async global->LDS, 16B per lane; LDS dst is wave-uniform base + lane*16
__device__ __forceinline__ void lds_cp16(void* lds, const void* g) {
  __builtin_amdgcn_global_load_lds(
      (__attribute__((address_space(1))) void*)(uintptr_t)g,
      (__attribute__((address_space(3))) void*)(uintptr_t)lds, 16, 0, 0);
}

// Stage a [R rows x K cols] bf16 tile into chunked LDS: (r,k) -> (k>>5)*(R*32)+r*32+(k&31).
template <int R, int K>
__device__ __forceinline__ void stage_tile(bf16_t* lds, const bf16_t* g, int ldg, int tid) {
  constexpr int TOT = R * K;
  constexpr int CH = R * 32;
  constexpr int ITERS = TOT / 2048;  // 256 threads * 8 elems
  const int wave = tid >> 6;
#pragma unroll
  for (int i = 0; i < ITERS; ++i) {
    int linear = i * 2048 + tid * 8;
    int chunk = linear / CH;
    int rem = linear % CH;
    int r = rem >> 5;
    int c = rem & 31;
    lds_cp16(lds + i * 2048 + wave * 512, g + r * ldg + chunk * 32 + c);
  }
}

__device__ __forceinline__ bf16x8 frag_ld(const bf16_t* lds_chunk, int row, int lane) {
  return *(const bf16x8*)(lds_chunk + row * 32 + ((lane >> 4) << 3));
}

// In-register P^T -> A-fragment transform (VERIFIED rounds 5-15).
// NOTE: the s_setprio brackets around the MFMA clusters in pass_b are REQUIRED for
// correctness with this transform -- removing them (round 16) corrupts the output
// (compiler reorders around the asm/ds_swizzle cluster). Do not remove.
// Input: pa = exp2'd P rows ms=0 (r=0..3), pb = ms=1; this lane = (quad, l15).
// Source layout: P[m=ms*16+quad*4+r][n=nsub*16+l15]. Output: A-frag bf16x8 with
// element jj = P[m=quad*8+jj][n=nsub*16+l15].
// After v_permlane32_swap(a,b): a=X0={a.lo,b.lo}, b=X1={a.hi,b.hi};
// word0 = hi16 ? swz16(X1) : X0 ; word2 = hi16 ? X1 : swz16(X0)  (same for Y from a1,b1).
__device__ __forceinline__ bf16x8 p_transpose(f32x4 pa, f32x4 pb, bool hi16) {
  uint32_t a0, a1, b0, b1;
  asm("v_cvt_pk_bf16_f32 %0, %1, %2" : "=v"(a0) : "v"(pa[0]), "v"(pa[1]));
  asm("v_cvt_pk_bf16_f32 %0, %1, %2" : "=v"(a1) : "v"(pa[2]), "v"(pa[3]));
  asm("v_cvt_pk_bf16_f32 %0, %1, %2" : "=v"(b0) : "v"(pb[0]), "v"(pb[1]));
  asm("v_cvt_pk_bf16_f32 %0, %1, %2" : "=v"(b1) : "v"(pb[2]), "v"(pb[3]));
  asm("v_permlane32_swap_b32 %0, %1" : "+v"(a0), "+v"(b0));  // a0=X0, b0=X1
  asm("v_permlane32_swap_b32 %0, %1" : "+v"(a1), "+v"(b1));  // a1=Y0, b1=Y1
  uint32_t sX0 = (uint32_t)__builtin_amdgcn_ds_swizzle((int)a0, 0x401F);  // lane^16
  uint32_t sX1 = (uint32_t)__builtin_amdgcn_ds_swizzle((int)b0, 0x401F);
  uint32_t sY0 = (uint32_t)__builtin_amdgcn_ds_swizzle((int)a1, 0x401F);
  uint32_t sY1 = (uint32_t)__builtin_amdgcn_ds_swizzle((int)b1, 0x401F);
  union {
    uint32_t u[4];
    bf16x8 v;
  } r;
  r.u[0] = hi16 ? sX1 : a0;
  r.u[1] = hi16 ? sY1 : a1;
  r.u[2] = hi16 ? b0 : sX0;
  r.u[3] = hi16 ? b1 : sY0;
  return r.v;
}

// ---------- elementwise f32 -> bf16 convert ----------
__global__ void cvt_kernel(const float* __restrict__ src, bf16_t* __restrict__ dst) {
  const int i = (blockIdx.x * 256 + threadIdx.x) * 4;
  float4 v = *(const float4*)&src[i];
  bf16x4 o;
  o[0] = (bf16_t)v.x;
  o[1] = (bf16_t)v.y;
  o[2] = (bf16_t)v.z;
  o[3] = (bf16_t)v.w;
  *(bf16x4*)&dst[i] = o;
}

// ---------- merged tiled transpose for Wq/Wk/Wv: f32 [8][1024][128] -> bf16 [8][128][1024]
__global__ void transpose_qkv_k(const float* __restrict__ Wq, const float* __restrict__ Wk,
                                const float* __restrict__ Wv, bf16_t* __restrict__ Wt) {
  __shared__ alignas(16) bf16_t tile[64][72];
  const int t = threadIdx.x;
  const int z = blockIdx.z;
  const int proj = z >> 3, mat = z & 7;
  const float* src = (proj == 0 ? Wq : proj == 1 ? Wk : Wv);
  const int R = 1024, C = 128;
  const int r0 = blockIdx.x * 64, c0 = blockIdx.y * 64;
  const float* s = src + (size_t)mat * R * C;
  bf16_t* d = Wt + (size_t)proj * 1048576 + (size_t)mat * R * C;
  const int rl = t >> 3, cl = (t & 7) * 8;
#pragma unroll
  for (int half = 0; half < 2; ++half) {
    const int r = r0 + rl + half * 32;
    float4 a = *(const float4*)&s[(size_t)r * C + c0 + cl];
    float4 b = *(const float4*)&s[(size_t)r * C + c0 + cl + 4];
    tile[cl + 0][rl + half * 32] = (bf16_t)a.x;
    tile[cl + 1][rl + half * 32] = (bf16_t)a.y;
    tile[cl + 2][rl + half * 32] = (bf16_t)a.z;
    tile[cl + 3][rl + half * 32] = (bf16_t)a.w;
    tile[cl + 4][rl + half * 32] = (bf16_t)b.x;
    tile[cl + 5][rl + half * 32] = (bf16_t)b.y;
    tile[cl + 6][rl + half * 32] = (bf16_t)b.z;
    tile[cl + 7][rl + half * 32] = (bf16_t)b.w;
  }
  __syncthreads();
  const int cl2 = t >> 3, rl2 = (t & 7) * 8;
  *(bf16x8*)&d[(size_t)(c0 + cl2) * R + r0 + rl2] = *(const bf16x8*)&tile[cl2][rl2];
  *(bf16x8*)&d[(size_t)(c0 + cl2 + 32) * R + r0 + rl2] = *(const bf16x8*)&tile[cl2 + 32][rl2];
}

// ---------- projections (round-11 verified BK=64 form) ----------
// Qf/Kf: [h][nt(256)][ks(4)][lane(64)][8]; Vf: [h][mb(128)][es(8)][lane(64)][8]
__global__ __launch_bounds__(256, 2) void proj_kernel(const bf16_t* __restrict__ X,
                                                      const bf16_t* __restrict__ Wt,
                                                      const float* __restrict__ bq,
                                                      const float* __restrict__ bk,
                                                      const float* __restrict__ bv,
                                                      bf16_t* __restrict__ qkv) {
  __shared__ alignas(16) char smem[34816];  // As(16K)+Bs(16K) in loop; Ct[128][136] epilogue
  bf16_t* As = (bf16_t*)smem;
  bf16_t* Bs = (bf16_t*)(smem + 16384);
  const int t = threadIdx.x, lane = t & 63, w = t >> 6;
  const int l15 = lane & 15, quad = lane >> 4;
  const int ntile = blockIdx.x, mat = blockIdx.y;
  const bf16_t* a0 = X + (size_t)ntile * 128 * 1024;
  const bf16_t* b0 = Wt + (size_t)mat * 131072;
  f32x4 acc[4][4] = {};
  const int rb = (w >> 1) * 64, cb = (w & 1) * 64;
  for (int k0 = 0; k0 < 1024; k0 += 64) {
    stage_tile<128, 64>(As, a0 + k0, 1024, t);
    stage_tile<128, 64>(Bs, b0 + k0, 1024, t);
    __syncthreads();
#pragma unroll
    for (int kk = 0; kk < 2; ++kk) {
      bf16x8 af[4], bfr[4];
#pragma unroll
      for (int i = 0; i < 4; ++i) af[i] = frag_ld(As + kk * 4096, rb + i * 16 + l15, lane);
#pragma unroll
      for (int j = 0; j < 4; ++j) bfr[j] = frag_ld(Bs + kk * 4096, cb + j * 16 + l15, lane);
#pragma unroll
      for (int i = 0; i < 4; ++i)
#pragma unroll
        for (int j = 0; j < 4; ++j) acc[i][j] = MFMA_16x16x32(af[i], bfr[j], acc[i][j]);
    }
    __syncthreads();
  }
  const int proj = mat >> 3, h = mat & 7;
  const float* bias = (proj == 0 ? bq : proj == 1 ? bk : bv) + h * 128;
  bf16_t* Ct = (bf16_t*)smem;  // safe: loop ended with __syncthreads
  bf16_t* dst = qkv + (size_t)proj * 4194304 + (size_t)h * 524288;
  if (proj < 2) {
    // n-major bounce [n][e], pitch 136 (keeps 16B alignment, breaks pow2 stride)
#pragma unroll
    for (int i = 0; i < 4; ++i)
#pragma unroll
      for (int j = 0; j < 4; ++j) {
        const int e = cb + j * 16 + l15;
        const float bval = bias[e];
#pragma unroll
        for (int r = 0; r < 4; ++r)
          Ct[(rb + i * 16 + quad * 4 + r) * 136 + e] = (bf16_t)(acc[i][j][r] + bval);
      }
    __syncthreads();
#pragma unroll
    for (int u = 0; u < 2; ++u) {
      const int nt = w * 2 + u;
#pragma unroll
      for (int ks = 0; ks < 4; ++ks) {
        bf16x8 f = *(const bf16x8*)&Ct[(nt * 16 + l15) * 136 + ks * 32 + quad * 8];
        *(bf16x8*)&dst[(((size_t)(ntile * 8 + nt)) * 4 + ks) * 512 + lane * 8] = f;
      }
    }
  } else {
    // e-major bounce [e][m] (m = this block's n rows), b64 writes / b128 reads
#pragma unroll
    for (int i = 0; i < 4; ++i)
#pragma unroll
      for (int j = 0; j < 4; ++j) {
        const int e = cb + j * 16 + l15;
        const float bval = bias[e];
        bf16x4 pv;
#pragma unroll
        for (int r = 0; r < 4; ++r) pv[r] = (bf16_t)(acc[i][j][r] + bval);
        *(bf16x4*)&Ct[e * 136 + rb + i * 16 + quad * 4] = pv;
      }
    __syncthreads();
#pragma unroll
    for (int es = 0; es < 8; ++es) {
      bf16x8 f = *(const bf16x8*)&Ct[(es * 16 + l15) * 136 + w * 32 + quad * 8];
      *(bf16x8*)&dst[(((size_t)(ntile * 4 + w)) * 8 + es) * 512 + lane * 8] = f;
    }
  }
}

// ---------- pass A: l2c[h][m] = log2( sum_n exp2(c1 * q[n].k[m]) ) ----------
__global__ __launch_bounds__(256, 2) void pass_a_kernel(const bf16_t* __restrict__ Qf,
                                                        const bf16_t* __restrict__ Kf,
                                                        float* __restrict__ l2c) {
  __shared__ alignas(16) float csred[4][64];
  const int t = threadIdx.x, lane = t & 63, w = t >> 6;
  const int l15 = lane & 15;
  const int h = blockIdx.x, mtile = blockIdx.y;
  const bf16_t* Qh = Qf + (size_t)h * 524288;
  const bf16_t* Kh = Kf + (size_t)h * 524288;
  bf16x8 kf[16];  // B-operand, 64m resident
#pragma unroll
  for (int mg = 0; mg < 4; ++mg)
#pragma unroll
    for (int ks = 0; ks < 4; ++ks)
      kf[mg * 4 + ks] = *(const bf16x8*)&Kh[((mtile * 4 + mg) * 4 + ks) * 512 + lane * 8];
  float cs[4] = {0.f, 0.f, 0.f, 0.f};
  uint32_t qo = w * 2048 + lane * 8;
  bf16x8 af[4];
#pragma unroll
  for (int ks = 0; ks < 4; ++ks) af[ks] = *(const bf16x8*)&Qh[qo + ks * 512];
  for (int it = 0; it < 64; ++it) {
    f32x4 c[4] = {};
#pragma unroll
    for (int ks = 0; ks < 4; ++ks)
#pragma unroll
      for (int mg = 0; mg < 4; ++mg) c[mg] = MFMA_16x16x32(af[ks], kf[mg * 4 + ks], c[mg]);
    qo += 8192;  // 4 tiles ahead (tail overreads next region: allocated, harmless)
#pragma unroll
    for (int ks = 0; ks < 4; ++ks) af[ks] = *(const bf16x8*)&Qh[qo + ks * 512];
#pragma unroll
    for (int mg = 0; mg < 4; ++mg)
#pragma unroll
      for (int r = 0; r < 4; ++r) cs[mg] += EXP2(c[mg][r] * kC1);
  }
#pragma unroll
  for (int mg = 0; mg < 4; ++mg) {
    cs[mg] += __shfl_xor(cs[mg], 16, 64);
    cs[mg] += __shfl_xor(cs[mg], 32, 64);
  }
  if (lane < 16) {
#pragma unroll
    for (int mg = 0; mg < 4; ++mg) csred[w][mg * 16 + lane] = cs[mg];
  }
  __syncthreads();
  if (t < 64)
    l2c[(size_t)h * 4096 + mtile * 64 + t] =
        __builtin_log2f(csred[0][t] + csred[1][t] + csred[2][t] + csred[3][t]);
}

// ---------- pass B: z[n][e] = sum_m exp2(c1*s - l2c[m]) * v[m][e]; sigmoid; store f32 ----------
// Barrier-free main loop (round-15 verified, FINAL): K and V direct from L2 (frag-major;
// head h resident in XCD-h L2; per-iter K+V working set 32KB = L1-sized, npar-duplicate
// waves L1-served). V mapping == the verified LDS-staging identity. No staging, no vmcnt,
// no main-loop s_barrier. s_setprio brackets around MFMA clusters are REQUIRED for
// correctness (round-16 regression without them). LDS = 64KB epilogue reduction only.
__global__ __launch_bounds__(512, 2) void pass_b_kernel(const bf16_t* __restrict__ Qf,
                                                        const bf16_t* __restrict__ Kf,
                                                        const bf16_t* __restrict__ Vf,
                                                        const float* __restrict__ l2c,
                                                        float* __restrict__ out) {
  __shared__ alignas(16) char smem[65536];
  const int t = threadIdx.x, lane = t & 63, w = t >> 6;
  const int quad = lane >> 4, l15 = lane & 15;
  const bool hi16 = (lane & 16) != 0;
  const int npar = w & 3, mpar = w >> 2;
  const int h = blockIdx.x, ntile = blockIdx.y;
  const bf16_t* Kh = Kf + (size_t)h * 524288;  // head stride = 524288 ELEMENTS (1 MB)
  const bf16_t* Vh = Vf + (size_t)h * 524288;
  const bf16_t* Qh = Qf + (size_t)h * 524288;
  const float* lb = l2c + (size_t)h * 4096;

  // q B-operand fragments (col n = this wave's 32n), resident
  bf16x8 qf[2][4];
#pragma unroll
  for (int nsub = 0; nsub < 2; ++nsub)
#pragma unroll
    for (int ks = 0; ks < 4; ++ks)
      qf[nsub][ks] =
          *(const bf16x8*)&Qh[((ntile * 8 + npar * 2 + nsub) * 4 + ks) * 512 + lane * 8];
  // k A-fragments for it=0, direct from global (L2)
  bf16x8 kf[8];
  {
    const bf16_t* kg = Kh + mpar * 4096;
#pragma unroll
    for (int u = 0; u < 8; ++u) kf[u] = *(const bf16x8*)&kg[u * 512 + lane * 8];
  }
  // l2c guide values for it=0, register-prefetched
  f32x4 gc0 = *(const f32x4*)&lb[mpar * 32 + quad * 4];
  f32x4 gc1 = *(const f32x4*)&lb[mpar * 32 + 16 + quad * 4];
  f32x4 zacc[2][8] = {};

  // pipeline prologue: QK(0) into ccp; issue kf(1)
  f32x4 ccp[2][2] = {};
  __builtin_amdgcn_s_setprio(1);
#pragma unroll
  for (int ks = 0; ks < 4; ++ks)
#pragma unroll
    for (int ms = 0; ms < 2; ++ms)
#pragma unroll
      for (int nsub = 0; nsub < 2; ++nsub)
        ccp[ms][nsub] = MFMA_16x16x32(kf[ms * 4 + ks], qf[nsub][ks], ccp[ms][nsub]);
  __builtin_amdgcn_s_setprio(0);
  {
    const bf16_t* kg = Kh + 8192 + mpar * 4096;
#pragma unroll
    for (int u = 0; u < 8; ++u) kf[u] = *(const bf16x8*)&kg[u * 512 + lane * 8];
  }

  for (int it = 0; it < 64; ++it) {
    // issue V(it) loads first (independent; L2 latency hides under QK+exp2+transform)
    bf16x8 vfr[8];
    {
      const bf16_t* vg = Vh + (size_t)it * 8192 + mpar * 4096;
#pragma unroll
      for (int es = 0; es < 8; ++es) vfr[es] = *(const bf16x8*)&vg[es * 512 + lane * 8];
    }
    // ---- QK for it+1 (kf holds kf(it+1); register-only, overlaps finish(it)) ----
    f32x4 ccn[2][2] = {};
    __builtin_amdgcn_s_setprio(1);
#pragma unroll
    for (int ks = 0; ks < 4; ++ks)
#pragma unroll
      for (int ms = 0; ms < 2; ++ms)
#pragma unroll
        for (int nsub = 0; nsub < 2; ++nsub)
          ccn[ms][nsub] = MFMA_16x16x32(kf[ms * 4 + ks], qf[nsub][ks], ccn[ms][nsub]);
    __builtin_amdgcn_s_setprio(0);
    // issue kf(it+2) into the just-freed regs (WAR-safe; tail overreads into adjacent
    // Vf region: allocated, harmless)
    {
      const bf16_t* kg = Kh + (size_t)(it + 2) * 8192 + mpar * 4096;
#pragma unroll
      for (int u = 0; u < 8; ++u) kf[u] = *(const bf16x8*)&kg[u * 512 + lane * 8];
    }
    // ---- finish it: exp2 + in-register transpose (verified ds_swizzle form) ----
    bf16x8 pf[2];
#pragma unroll
    for (int nsub = 0; nsub < 2; ++nsub) {
      f32x4 pa, pb;
#pragma unroll
      for (int r = 0; r < 4; ++r) pa[r] = EXP2(ccp[0][nsub][r] * kC1 - gc0[r]);
#pragma unroll
      for (int r = 0; r < 4; ++r) pb[r] = EXP2(ccp[1][nsub][r] * kC1 - gc1[r]);
      pf[nsub] = p_transpose(pa, pb, hi16);
    }
    // prefetch g for it+1 (clamped at the tail)
    {
      const int stn = (it < 63 ? it + 1 : 63) * 2 + mpar;
      gc0 = *(const f32x4*)&lb[stn * 32 + quad * 4];
      gc1 = *(const f32x4*)&lb[stn * 32 + 16 + quad * 4];
    }
    // ---- PV(it) from registers ----
    __builtin_amdgcn_s_setprio(1);
#pragma unroll
    for (int es = 0; es < 8; ++es) {
#pragma unroll
      for (int nsub = 0; nsub < 2; ++nsub)
        zacc[nsub][es] = MFMA_16x16x32(pf[nsub], vfr[es], zacc[nsub][es]);
    }
    __builtin_amdgcn_s_setprio(0);
    // carry the pipeline register
#pragma unroll
    for (int ms = 0; ms < 2; ++ms)
#pragma unroll
      for (int nsub = 0; nsub < 2; ++nsub) ccp[ms][nsub] = ccn[ms][nsub];
  }
  // epilogue: merge mpar pairs via LDS, sigmoid, store f32
  float* red = (float*)smem;  // [npar][nsub*8+es][lane*4] = 16KB per npar
  if (mpar == 1) {
#pragma unroll
    for (int nsub = 0; nsub < 2; ++nsub)
#pragma unroll
      for (int es = 0; es < 8; ++es)
        *(f32x4*)&red[npar * 4096 + (nsub * 8 + es) * 256 + lane * 4] = zacc[nsub][es];
  }
  __syncthreads();
  if (mpar == 0) {
#pragma unroll
    for (int nsub = 0; nsub < 2; ++nsub) {
#pragma unroll
      for (int es = 0; es < 8; ++es) {
        f32x4 o = *(const f32x4*)&red[npar * 4096 + (nsub * 8 + es) * 256 + lane * 4];
        const int e = es * 16 + l15;
#pragma unroll
        for (int r = 0; r < 4; ++r) {
          const int n = ntile * 128 + npar * 32 + nsub * 16 + quad * 4 + r;
          const float z = zacc[nsub][es][r] + o[r];
          out[(size_t)n * 1024 + h * 128 + e] = 1.f / (1.f + EXP2(-z * kLog2e));
        }
      }
    }
  }
}

extern "C" void kernel_launch(void* const* d_in, const int* in_sizes, int n_in, void* d_out,
                              int out_size, void* d_ws, size_t ws_size, hipStream_t stream) {
  (void)in_sizes;
  (void)n_in;
  (void)out_size;
  (void)ws_size;
  const float* X = (const float*)d_in[0];
  const float* Wq = (const float*)d_in[1];
  const float* bq = (const float*)d_in[2];
  const float* Wk = (const float*)d_in[3];
  const float* bk = (const float*)d_in[4];
  const float* Wv = (const float*)d_in[5];
  const float* bv = (const float*)d_in[6];
  float* out = (float*)d_out;
  char* ws = (char*)d_ws;
  // byte layout (39.98 MB):
  //  [0,8M): Qf   [8M,16M): Kf   [16M,24M): Vf
  //  [24M,32M): Xb (cvt out, proj in)
  //  [32M,38M): Wt (dead after proj)
  //  [39845888,+128K): l2c
  bf16_t* Qf = (bf16_t*)(ws);
  bf16_t* Kf = (bf16_t*)(ws + 8388608);
  bf16_t* Vf = (bf16_t*)(ws + 16777216);
  bf16_t* Xb = (bf16_t*)(ws + 25165824);
  bf16_t* Wt = (bf16_t*)(ws + 33554432);
  float* l2c = (float*)(ws + 39845888);

  cvt_kernel<<<4096, 256, 0, stream>>>(X, Xb);
  transpose_qkv_k<<<dim3(16, 2, 24), 256, 0, stream>>>(Wq, Wk, Wv, Wt);
  proj_kernel<<<dim3(32, 24), 256, 0, stream>>>(Xb, Wt, bq, bk, bv, Qf);
  pass_a_kernel<<<dim3(8, 64), 256, 0, stream>>>(Qf, Kf, l2c);
  pass_b_kernel<<<dim3(8, 32), 512, 0, stream>>>(Qf, Kf, Vf, l2c, out);
}